// Round 1
// baseline (50.682 us; speedup 1.0000x reference)
//
#include <hip/hip_runtime.h>
#include <hip/hip_bf16.h>
#include <math.h>

// Problem constants (fixed by the reference):
//   D=5 directions, E=16 experts, B=64 batch, P=4096 patches/expert, W=3 window
//   Q,K,V: [D,E,B,P] f32; betas: [E,E] f32; temperature: [1] f32; routes: [E,W] int
//   out: [B, E*P] f32, out[b, e*P+p] = mean_d softmax_w(Q*c)_w . Vnbr_w

#define D_ 5
#define E_ 16
#define B_ 64
#define P_ 4096
#define W_ 3
#define ROWS (D_*E_*B_)   // 5120 (d,e,b) rows

// ---------------- Phase 1: Ksum / Vmean row reductions ----------------
// one block per (d,e,b) row; 256 threads; float4 loads
__global__ __launch_bounds__(256) void cga_phase1(
    const float* __restrict__ K, const float* __restrict__ V,
    float* __restrict__ ksum, float* __restrict__ vmean)
{
    const int row = blockIdx.x;                 // [0, 5120)
    const float4* k4 = (const float4*)(K + (size_t)row * P_);
    const float4* v4 = (const float4*)(V + (size_t)row * P_);
    const int t = threadIdx.x;

    float ks = 0.f, vs = 0.f;
    #pragma unroll
    for (int i = 0; i < 4; ++i) {               // 4 * 256 = 1024 float4 = 4096 floats
        float4 a = k4[t + i * 256];
        float4 b = v4[t + i * 256];
        ks += (a.x + a.y) + (a.z + a.w);
        vs += (b.x + b.y) + (b.z + b.w);
    }
    // wave-64 tree reduce
    #pragma unroll
    for (int off = 32; off > 0; off >>= 1) {
        ks += __shfl_down(ks, off);
        vs += __shfl_down(vs, off);
    }
    __shared__ float sk[4], sv[4];
    const int wid = t >> 6, lane = t & 63;
    if (lane == 0) { sk[wid] = ks; sv[wid] = vs; }
    __syncthreads();
    if (t == 0) {
        float kk = (sk[0] + sk[1]) + (sk[2] + sk[3]);
        float vv = (sv[0] + sv[1]) + (sv[2] + sv[3]);
        ksum[row]  = kk;
        vmean[row] = vv * (1.0f / (float)P_);
    }
}

// ---------------- Phase 2: stream Q, 3-way softmax, mean over d ----------------
__device__ __forceinline__ float attend1(float q, const float c[3], const float v[3])
{
    float s0 = q * c[0], s1 = q * c[1], s2 = q * c[2];
    float m  = fmaxf(fmaxf(s0, s1), s2);
    float e0 = __expf(s0 - m), e1 = __expf(s1 - m), e2 = __expf(s2 - m);
    float num = e0 * v[0] + e1 * v[1] + e2 * v[2];
    float den = e0 + e1 + e2;
    return num / den;
}

// grid = E*B*(P/1024) = 4096 blocks; 256 threads; 4 floats/thread/direction
__global__ __launch_bounds__(256) void cga_phase2(
    const float* __restrict__ Q,
    const float* __restrict__ ksum, const float* __restrict__ vmean,
    const float* __restrict__ betas, const float* __restrict__ temp,
    const int* __restrict__ routes,
    float* __restrict__ out)
{
    const int blk   = blockIdx.x;
    const int chunk = blk & 3;        // 4 chunks of 1024 patches per (e,b)
    const int eb    = blk >> 2;
    const int b     = eb & (B_ - 1);
    const int e     = eb >> 6;

    __shared__ float sc[D_][W_];      // score coeffs  c[d][w] = Ksum*scale*beta
    __shared__ float sv[D_][W_];      // value coeffs  v[d][w] = Vmean

    if (threadIdx.x < D_ * W_) {
        const int d = threadIdx.x / W_;
        const int w = threadIdx.x % W_;
        const int rw = routes[e * W_ + w];
        const float scale = 1.0f / (11.313708498984760f * fabsf(temp[0])); // sqrt(128)
        float bw = 1.0f;
        if (rw != e) {
            float bb = betas[e * E_ + rw];
            bw = 1.0f / (1.0f + __expf(-bb));
        }
        const int idx = (d * E_ + rw) * B_ + b;
        sc[d][w] = ksum[idx] * scale * bw;
        sv[d][w] = vmean[idx];
    }
    __syncthreads();

    float rc[D_][W_], rv[D_][W_];
    #pragma unroll
    for (int d = 0; d < D_; ++d)
        #pragma unroll
        for (int w = 0; w < W_; ++w) { rc[d][w] = sc[d][w]; rv[d][w] = sv[d][w]; }

    const int p0 = chunk * 1024 + (int)threadIdx.x * 4;

    float4 acc = make_float4(0.f, 0.f, 0.f, 0.f);
    #pragma unroll
    for (int d = 0; d < D_; ++d) {
        const size_t qoff = ((size_t)((d * E_ + e) * B_ + b)) * P_ + p0;
        const float4 q = *(const float4*)(Q + qoff);
        acc.x += attend1(q.x, rc[d], rv[d]);
        acc.y += attend1(q.y, rc[d], rv[d]);
        acc.z += attend1(q.z, rc[d], rv[d]);
        acc.w += attend1(q.w, rc[d], rv[d]);
    }
    const float inv_d = 1.0f / (float)D_;
    acc.x *= inv_d; acc.y *= inv_d; acc.z *= inv_d; acc.w *= inv_d;

    // out[b, e*P + p]
    float4* op = (float4*)(out + (size_t)b * (E_ * P_) + (size_t)e * P_ + p0);
    *op = acc;
}

extern "C" void kernel_launch(void* const* d_in, const int* in_sizes, int n_in,
                              void* d_out, int out_size, void* d_ws, size_t ws_size,
                              hipStream_t stream) {
    const float* Q     = (const float*)d_in[0];
    const float* K     = (const float*)d_in[1];
    const float* V     = (const float*)d_in[2];
    const float* betas = (const float*)d_in[3];
    const float* temp  = (const float*)d_in[4];
    const int*   routes= (const int*)d_in[5];
    float* out = (float*)d_out;

    float* ksum  = (float*)d_ws;          // ROWS floats
    float* vmean = ksum + ROWS;           // ROWS floats  (40 KB total)

    cga_phase1<<<ROWS, 256, 0, stream>>>(K, V, ksum, vmean);
    cga_phase2<<<E_ * B_ * (P_ / 1024), 256, 0, stream>>>(
        Q, ksum, vmean, betas, temp, routes, out);
}